// Round 14
// baseline (202.631 us; speedup 1.0000x reference)
//
#include <hip/hip_runtime.h>
#include <cstdint>

typedef unsigned short u16;
typedef __bf16 bf16x8 __attribute__((ext_vector_type(8)));
typedef float f32x4 __attribute__((ext_vector_type(4)));
typedef short s4 __attribute__((ext_vector_type(4)));

#define T_SEQ 2048
#define NH 16
// split-attn scratch (per parity buffer): O bf16 tiles, then (m,l) fp32 pairs
#define P_TILES 992            // 32 bh * 31 split q-tiles
#define P_O_U16 (P_TILES * 4096)      // 4063232 u16 = 8.13 MB
#define P_ML_OFF_F 2031616            // float offset of ML region (= P_O_U16/2)
#define P_ML 128                      // floats per tile (64 rows * 2)

// RTNE float -> bf16 bits
__device__ __forceinline__ u16 f2bf(float f) {
  union { float f; uint32_t u; } x; x.f = f;
  uint32_t r = (x.u + 0x7fffu + ((x.u >> 16) & 1u)) >> 16;
  return (u16)r;
}

__device__ __forceinline__ float bf2f(u16 b) {
  union { uint32_t u; float f; } x; x.u = ((uint32_t)b) << 16; return x.f;
}

// pack two floats -> two bf16 (RTNE)
__device__ __forceinline__ uint32_t pk2bf(float a, float b) {
  union { float f; uint32_t u; } x, y; x.f = a; y.f = b;
  uint32_t lo = (x.u + 0x7fffu + ((x.u >> 16) & 1u)) >> 16;
  uint32_t hi = (y.u + 0x7fffu + ((y.u >> 16) & 1u)) >> 16;
  return lo | (hi << 16);
}

// 8 fp32 -> 8 bf16 (one uint4 store)
__device__ __forceinline__ void cvt8(u16* dst, const float* src) {
  float4 a = *(const float4*)src;
  float4 b = *(const float4*)(src + 4);
  uint4 o;
  o.x = pk2bf(a.x, a.y); o.y = pk2bf(a.z, a.w);
  o.z = pk2bf(b.x, b.y); o.w = pk2bf(b.z, b.w);
  *(uint4*)dst = o;
}

// fused fp32 -> bf16 conversion of x, w_qkv, w_o (dst regions contiguous in ws)
__global__ __launch_bounds__(256) void cvt_all(const float* __restrict__ x,
                                               const float* __restrict__ wq,
                                               const float* __restrict__ wo,
                                               u16* __restrict__ dst) {
  int i = blockIdx.x * 256 + threadIdx.x;
  const float* src; int off;
  if (i < 524288)      { src = x;  off = 0; }
  else if (i < 917504) { src = wq; off = 524288; }
  else                 { src = wo; off = 917504; }
  cvt8(&dst[(size_t)i * 8], &src[(size_t)(i - off) * 8]);
}

// f32x4 accumulator quad -> 4 bf16
__device__ __forceinline__ s4 cvt4(f32x4 v) {
  union { __bf16 b[4]; s4 s; } u;
  u.b[0] = (__bf16)v[0]; u.b[1] = (__bf16)v[1];
  u.b[2] = (__bf16)v[2]; u.b[3] = (__bf16)v[3];
  return u.s;
}

__device__ __forceinline__ f32x4 mfma16(s4 a, s4 b, f32x4 c) {
#if __has_builtin(__builtin_amdgcn_mfma_f32_16x16x16bf16_1k)
  return __builtin_amdgcn_mfma_f32_16x16x16bf16_1k(a, b, c, 0, 0, 0);
#else
  asm("v_mfma_f32_16x16x16_bf16 %0, %1, %2, %0" : "+v"(c) : "v"(a), "v"(b));
  return c;
#endif
}

// native 2^x
__device__ __forceinline__ float exp2fast(float x) {
#if __has_builtin(__builtin_amdgcn_exp2f)
  return __builtin_amdgcn_exp2f(x);
#else
  float r; asm("v_exp_f32 %0, %1" : "=v"(r) : "v"(x)); return r;
#endif
}

// async 16B global -> LDS (HW scatters lane i at ldsbase + i*16)
__device__ __forceinline__ void gl_lds(const u16* g, u16* ldsbase) {
  __builtin_amdgcn_global_load_lds(
      (const __attribute__((address_space(1))) void*)g,
      (__attribute__((address_space(3))) void*)ldsbase, 16, 0, 0);
}

// C[M,N] = A[M,K] * W[N,K]^T. A,W bf16; C fp32 (CF32) or bf16 ws.
// KV: k cols (1024..2047) -> qkv bf16 + outk fp32; v cols (>=2048) ->
//     outv fp32 + TRANSPOSED bf16 into vt (fused transpose_v).
// tile BMx128, BK=64, 512 threads = 8 waves, each (BM/2)x32.
// global_load_lds staging, XOR-swizzled linear LDS, bijective XCD swizzle.
// T3-minimum 2-phase dbuf.  (Round-12 winner, unchanged.)
template <bool CF32, bool KV, int BM>
__global__ __launch_bounds__(512) void gemm_bt(
    const u16* __restrict__ A, const u16* __restrict__ W,
    void* __restrict__ Cp, float* __restrict__ outk, float* __restrict__ outv,
    u16* __restrict__ vtp, int M, int N, int K) {
  constexpr int WM = BM / 2;            // wave m-extent
  constexpr int MI = WM / 16;           // m-frags per wave
  constexpr int NJ = 2;                 // n-frags per wave (32 cols)
  __shared__ __align__(16) u16 As[2][BM * 64];
  __shared__ __align__(16) u16 Bs[2][128 * 64];
  const int tid  = threadIdx.x;
  const int bid  = blockIdx.y * gridDim.x + blockIdx.x;
  const int per  = (gridDim.x * gridDim.y) >> 3;
  const int swz  = (bid & 7) * per + (bid >> 3);
  const int n0   = (swz % gridDim.x) * 128;
  const int m0   = (swz / gridDim.x) * BM;
  const int lane = tid & 63;
  const int wave = tid >> 6;            // 0..7
  const int wm   = (wave >> 2) * WM;
  const int wn   = (wave & 3) * 32;
  const int l15  = lane & 15;
  const int quad = lane >> 4;
  const int srow = lane >> 3;   // row within 8-row stage group
  const int sc   = lane & 7;    // 16B chunk within row

  f32x4 acc[MI][NJ];
#pragma unroll
  for (int i = 0; i < MI; i++)
#pragma unroll
    for (int j = 0; j < NJ; j++) acc[i][j] = (f32x4){0.f, 0.f, 0.f, 0.f};

  auto stage = [&](int d, int k0) {
#pragma unroll
    for (int i = 0; i < BM / 64; i++) {     // A: BM/8 groups over 8 waves
      int r0  = (i * 8 + wave) * 8;
      int row = r0 + srow;
      int gc  = (sc ^ (row & 7)) << 3;      // pre-swizzled source column
      gl_lds(&A[(size_t)(m0 + row) * K + k0 + gc], &As[d][r0 * 64]);
    }
#pragma unroll
    for (int i = 0; i < 2; i++) {           // B: 16 groups over 8 waves
      int r0  = (i * 8 + wave) * 8;
      int row = r0 + srow;
      int gc  = (sc ^ (row & 7)) << 3;
      gl_lds(&W[(size_t)(n0 + row) * K + k0 + gc], &Bs[d][r0 * 64]);
    }
  };

  stage(0, 0);
  asm volatile("s_waitcnt vmcnt(0)" ::: "memory");
  __builtin_amdgcn_s_barrier();
  __builtin_amdgcn_sched_barrier(0);

  const int NT = K >> 6;
  int cur = 0;
  for (int t = 0; t < NT; t++) {
    if (t + 1 < NT) stage(cur ^ 1, (t + 1) * 64);  // in flight under compute
#pragma unroll
    for (int kk = 0; kk < 64; kk += 32) {
      bf16x8 af[MI], bfr[NJ];
#pragma unroll
      for (int i = 0; i < MI; i++) {
        int arow = wm + i * 16 + l15;
        af[i] = *(const bf16x8*)((const char*)&As[cur][0] + arow * 128 +
                                 ((((kk >> 3) + quad) ^ (arow & 7)) << 4));
      }
#pragma unroll
      for (int j = 0; j < NJ; j++) {
        int brow = wn + j * 16 + l15;
        bfr[j] = *(const bf16x8*)((const char*)&Bs[cur][0] + brow * 128 +
                                  ((((kk >> 3) + quad) ^ (brow & 7)) << 4));
      }
#pragma unroll
      for (int i = 0; i < MI; i++)
#pragma unroll
        for (int j = 0; j < NJ; j++)
          acc[i][j] = __builtin_amdgcn_mfma_f32_16x16x32_bf16(af[i], bfr[j], acc[i][j], 0, 0, 0);
    }
    asm volatile("s_waitcnt vmcnt(0)" ::: "memory");
    __builtin_amdgcn_s_barrier();
    __builtin_amdgcn_sched_barrier(0);
    cur ^= 1;
  }
#pragma unroll
  for (int i = 0; i < MI; i++)
#pragma unroll
    for (int j = 0; j < NJ; j++) {
      const int row0 = m0 + wm + i * 16 + quad * 4;  // 4 consecutive rows
      const int col  = n0 + wn + j * 16 + l15;
      if constexpr (CF32) {
#pragma unroll
        for (int r = 0; r < 4; r++)
          ((float*)Cp)[(size_t)(row0 + r) * N + col] = acc[i][j][r];
      } else if (KV && col >= 2048) {
        // v: fp32 output + transposed bf16 into vt (4 consecutive t -> 8B)
        const int hd = col - 2048;
        const int b_ = row0 >> 11, t_ = row0 & 2047;
        uint2 pk;
        pk.x = pk2bf(acc[i][j][0], acc[i][j][1]);
        pk.y = pk2bf(acc[i][j][2], acc[i][j][3]);
        *(uint2*)&vtp[((size_t)(b_ * NH + (hd >> 6)) * 64 + (hd & 63)) * 2048 + t_] = pk;
#pragma unroll
        for (int r = 0; r < 4; r++)
          outv[(size_t)(row0 + r) * 1024 + hd] = acc[i][j][r];
      } else {
#pragma unroll
        for (int r = 0; r < 4; r++) {
          float v = acc[i][j][r];
          ((u16*)Cp)[(size_t)(row0 + r) * N + col] = f2bf(v);
          if constexpr (KV) {
            if (col >= 1024) outk[(size_t)(row0 + r) * 1024 + (col - 1024)] = v;
          }
        }
      }
    }
}

// Flash-style causal attention, swapped QK^T (S^T = mfma(K,Q)), SPLIT-K:
// every q-tile qt>=1 is computed by TWO independent blocks (even k-tiles /
// odd k-tiles), each an online-softmax pass of <=16 steps -> critical path
// halves vs the 32-step monolithic tile.  Split parts store unnormalized O
// (bf16) + per-row (m,l) fp32 to scratch; merge_attn combines.  qt=0 writes
// ao directly.  Grid 63x32; bx = rank in DESCENDING part length (long parts
// dispatch first): rank<62: qt=31-(rank>>1), parity=rank&1; rank 62: qt=0.
// Scratch: pA in `out` region (gemm2 overwrites it later); pB in xb+wqb
// region (dead after gemm1) -- wob is NOT touched (round-13 bug fixed).
// 2-buffer K/V LDS pipeline, one barrier/step (round-9 rhythm), k-stride 2.
__global__ __launch_bounds__(256) void attn(const u16* __restrict__ qkv,
                                            const u16* __restrict__ vt,
                                            u16* __restrict__ o,
                                            u16* __restrict__ poA,
                                            u16* __restrict__ poB) {
  __shared__ __align__(16) u16 Ks[2][64 * 64];
  __shared__ __align__(16) u16 Vts[2][64 * 64];

  const int tid  = threadIdx.x;
  const int bx   = blockIdx.x;          // rank 0..62
  const int by   = blockIdx.y;          // bh = b*16+h
  const int b    = by >> 4, h = by & 15;
  const int lane = tid & 63, wave = tid >> 6;
  const int l15  = lane & 15, quad = lane >> 4;
  const int srow = lane >> 3, sc = lane & 7;
  const size_t qbase = (size_t)b * T_SEQ * 3072;
  const size_t vbase = (size_t)(b * NH + h) * 64 * 2048;
  const float C = 0.1803368801f;        // 0.125 * log2(e)

  int qt, parity;
  if (bx == 62) { qt = 0; parity = 0; }
  else          { qt = 31 - (bx >> 1); parity = bx & 1; }
  const int nsteps = (parity == 0) ? (qt / 2 + 1) : ((qt + 1) / 2);
  const bool split = (qt >= 1);

  const int wq0  = qt * 64 + wave * 16;
  const int qrow = wq0 + l15;

  // Q fragments (B-operand: n=l15 -> q row), loaded once from global
  const u16* qp = &qkv[qbase + (size_t)qrow * 3072 + h * 64];
  const bf16x8 qf0 = *(const bf16x8*)&qp[quad * 8];
  const bf16x8 qf1 = *(const bf16x8*)&qp[32 + quad * 8];

  f32x4 acc_o[4];
#pragma unroll
  for (int n = 0; n < 4; n++) acc_o[n] = (f32x4){0.f, 0.f, 0.f, 0.f};
  float m2run = -1e30f, lrun = 0.f;

  // async stage of k-tile kt into buffer buf: 4 gl_lds per wave
  auto stage = [&](int buf, int kt) {
    const int k0 = kt * 64;
#pragma unroll
    for (int i = 0; i < 2; i++) {
      int r0  = (wave * 2 + i) * 8;
      int row = r0 + srow;
      int gc  = (sc ^ (row & 7)) << 3;
      gl_lds(&qkv[qbase + (size_t)(k0 + row) * 3072 + 1024 + h * 64 + gc], &Ks[buf][r0 * 64]);
      gl_lds(&vt[vbase + (size_t)row * 2048 + k0 + gc], &Vts[buf][r0 * 64]);
    }
  };

  stage(0, parity);

  for (int s = 0; s < nsteps; s++) {
    const int cur = s & 1;
    const int kt  = parity + 2 * s;
    asm volatile("s_waitcnt vmcnt(0)" ::: "memory");
    __builtin_amdgcn_s_barrier();
    __builtin_amdgcn_sched_barrier(0);

    if (s + 1 < nsteps) stage(cur ^ 1, parity + 2 * (s + 1));

    const int k0 = kt * 64;

    // S^T[j]: row (quad*4+r) = k_local, col l15 = q  (swizzled Ks reads)
    f32x4 sacc[4];
#pragma unroll
    for (int j = 0; j < 4; j++) sacc[j] = (f32x4){0.f, 0.f, 0.f, 0.f};
    __builtin_amdgcn_s_setprio(1);
#pragma unroll
    for (int j = 0; j < 4; j++) {
      int krow = j * 16 + l15;
      const char* kb = (const char*)&Ks[cur][0] + krow * 128;
      bf16x8 kfa = *(const bf16x8*)(kb + ((quad ^ (krow & 7)) << 4));
      bf16x8 kfb = *(const bf16x8*)(kb + (((4 + quad) ^ (krow & 7)) << 4));
      sacc[j] = __builtin_amdgcn_mfma_f32_16x16x32_bf16(kfa, qf0, sacc[j], 0, 0, 0);
      sacc[j] = __builtin_amdgcn_mfma_f32_16x16x32_bf16(kfb, qf1, sacc[j], 0, 0, 0);
    }
    __builtin_amdgcn_s_setprio(0);

    if (kt == qt) {  // diagonal tile: causal mask on raw scores
#pragma unroll
      for (int j = 0; j < 4; j++)
#pragma unroll
        for (int r = 0; r < 4; r++) {
          int k = k0 + j * 16 + quad * 4 + r;
          if (k > qrow) sacc[j][r] = -1e30f;
        }
    }

    // row max, tree-shaped
    float mj[4];
#pragma unroll
    for (int j = 0; j < 4; j++)
      mj[j] = fmaxf(fmaxf(sacc[j][0], sacc[j][1]), fmaxf(sacc[j][2], sacc[j][3]));
    float mx = fmaxf(fmaxf(mj[0], mj[1]), fmaxf(mj[2], mj[3]));
    mx = fmaxf(mx, __shfl_xor(mx, 16));
    mx = fmaxf(mx, __shfl_xor(mx, 32));
    const float m2x = mx * C;

    // defer-max: only rescale when the max grew by > 8 (log2 domain)
    if (!__all(m2x <= m2run + 8.0f)) {
      const float m2new = fmaxf(m2run, m2x);
      const float alpha = exp2fast(m2run - m2new);
      lrun *= alpha;
      m2run = m2new;
#pragma unroll
      for (int r = 0; r < 4; r++) {
        float ar = __shfl(alpha, quad * 4 + r);
#pragma unroll
        for (int n = 0; n < 4; n++) acc_o[n][r] *= ar;
      }
    }

    // p = exp2(s*C - m2run); tree sum
    const float nm = m2run;
    float ts[4];
#pragma unroll
    for (int j = 0; j < 4; j++) {
#pragma unroll
      for (int r = 0; r < 4; r++) sacc[j][r] = exp2fast(fmaf(sacc[j][r], C, -nm));
      ts[j] = (sacc[j][0] + sacc[j][1]) + (sacc[j][2] + sacc[j][3]);
    }
    float sum = (ts[0] + ts[1]) + (ts[2] + ts[3]);
    sum += __shfl_xor(sum, 16);
    sum += __shfl_xor(sum, 32);
    lrun += sum;

    // P -> bf16 A-frags (m=l15 -> q, k = quad*4+e), in-register
    s4 pa[4];
#pragma unroll
    for (int j = 0; j < 4; j++) pa[j] = cvt4(sacc[j]);

    // PV: B-frag = V^T[d = n*16+l15][k0 + j*16+quad*4 ..+3], swizzled b64
    __builtin_amdgcn_s_setprio(1);
#pragma unroll
    for (int j = 0; j < 4; j++)
#pragma unroll
      for (int n = 0; n < 4; n++) {
        int vrow = n * 16 + l15;
        int ch = (j * 2 + (quad >> 1)) ^ (vrow & 7);
        const s4 vf = *(const s4*)((const char*)&Vts[cur][0] + vrow * 128 +
                                   (ch << 4) + ((quad & 1) << 3));
        acc_o[n] = mfma16(pa[j], vf, acc_o[n]);
      }
    __builtin_amdgcn_s_setprio(0);
  }

  if (split) {
    // store unnormalized partial: O bf16 + per-row (m,l) fp32
    const int t = by * 31 + (qt - 1);
    u16* po   = (parity == 0) ? poA : poB;
    float* ml = (float*)((parity == 0) ? poA : poB) + P_ML_OFF_F;
    u16* PO   = po + (size_t)t * 4096;
    float* ML = ml + (size_t)t * P_ML;
#pragma unroll
    for (int r = 0; r < 4; r++) {
      int row = wave * 16 + quad * 4 + r;
#pragma unroll
      for (int n = 0; n < 4; n++)
        PO[row * 64 + n * 16 + l15] = f2bf(acc_o[n][r]);
    }
    if (quad == 0) {
      int row = wave * 16 + l15;
      ML[row * 2]     = m2run;
      ML[row * 2 + 1] = lrun;
    }
  } else {
    const float linv = 1.0f / lrun;
#pragma unroll
    for (int r = 0; r < 4; r++) {
      const float lr = __shfl(linv, quad * 4 + r);
      const int row = wq0 + quad * 4 + r;
#pragma unroll
      for (int n = 0; n < 4; n++)
        o[(size_t)(b * T_SEQ + row) * 1024 + h * 64 + n * 16 + l15] =
            f2bf(acc_o[n][r] * lr);
    }
  }
}

// merge the two split-k partials of each q-tile (qt 1..31) -> bf16 ao.
// m = max(mA,mB); s* = 2^(m*-m); ao = (OA*sA + OB*sB) / (lA*sA + lB*sB).
__global__ __launch_bounds__(256) void merge_attn(const u16* __restrict__ poA,
                                                  const u16* __restrict__ poB,
                                                  u16* __restrict__ ao) {
  const int qt = blockIdx.x + 1;        // 1..31
  const int by = blockIdx.y;            // bh
  const int b  = by >> 4, h = by & 15;
  const int t  = by * 31 + (qt - 1);
  const int tid = threadIdx.x;
  const int row = tid >> 2;             // 0..63
  const int cg  = (tid & 3) * 16;       // 16-col group
  const u16* POA = poA + (size_t)t * 4096 + row * 64 + cg;
  const u16* POB = poB + (size_t)t * 4096 + row * 64 + cg;
  const float* MLA = (const float*)poA + P_ML_OFF_F + (size_t)t * P_ML + row * 2;
  const float* MLB = (const float*)poB + P_ML_OFF_F + (size_t)t * P_ML + row * 2;
  const float mA = MLA[0], lA = MLA[1];
  const float mB = MLB[0], lB = MLB[1];
  const float m  = fmaxf(mA, mB);
  const float sA = exp2fast(mA - m), sB = exp2fast(mB - m);
  const float inv = 1.0f / (lA * sA + lB * sB);
  const float fA = sA * inv, fB = sB * inv;
  union { uint4 v[2]; u16 s[16]; } A, B;
  A.v[0] = *(const uint4*)POA;  A.v[1] = *(const uint4*)(POA + 8);
  B.v[0] = *(const uint4*)POB;  B.v[1] = *(const uint4*)(POB + 8);
  float c[16];
#pragma unroll
  for (int k = 0; k < 16; k++)
    c[k] = bf2f(A.s[k]) * fA + bf2f(B.s[k]) * fB;
  uint4 o0, o1;
  o0.x = pk2bf(c[0], c[1]);   o0.y = pk2bf(c[2], c[3]);
  o0.z = pk2bf(c[4], c[5]);   o0.w = pk2bf(c[6], c[7]);
  o1.x = pk2bf(c[8], c[9]);   o1.y = pk2bf(c[10], c[11]);
  o1.z = pk2bf(c[12], c[13]); o1.w = pk2bf(c[14], c[15]);
  u16* dst = &ao[((size_t)(b * T_SEQ + qt * 64 + row)) * 1024 + h * 64 + cg];
  *(uint4*)dst = o0;
  *(uint4*)(dst + 8) = o1;
}

extern "C" void kernel_launch(void* const* d_in, const int* in_sizes, int n_in,
                              void* d_out, int out_size, void* d_ws, size_t ws_size,
                              hipStream_t stream) {
  const float* x     = (const float*)d_in[0];   // (2,2048,1024) fp32
  const float* w_qkv = (const float*)d_in[1];   // (3072,1024)   fp32
  const float* w_o   = (const float*)d_in[2];   // (1024,1024)   fp32
  float* out  = (float*)d_out;                  // fp32 (4096,1024)
  float* outk = out + (size_t)4194304;
  float* outv = out + (size_t)8388608;

  u16* qkv = (u16*)d_ws;                        // 4096*3072
  u16* vt  = qkv + (size_t)4096 * 3072;         // 32*64*2048
  u16* ao  = vt  + (size_t)4194304;             // 4096*1024
  u16* xb  = ao  + (size_t)4194304;             // 4096*1024
  u16* wqb = xb  + (size_t)4194304;             // 3072*1024
  u16* wob = wqb + (size_t)3145728;             // 1024*1024

  // split-k scratch (8.63 MB each, bf16 O + fp32 ML):
  //  pA -> out region [0 .. 8.63MB)   (gemm2 fully overwrites out afterwards)
  //  pB -> xb + head of wqb (dead after gemm1); wob is NOT touched.
  u16* poA = (u16*)out;
  u16* poB = xb;

  // 0. fused fp32 -> bf16 conversion (xb, wqb, wob contiguous)
  cvt_all<<<4096, 256, 0, stream>>>(x, w_qkv, w_o, xb);

  // 1. qkv(bf16 ws) = xb @ wqb^T; k -> qkv+outk; v -> outv + vt (fused
  //    transpose).  128x128 tile, 8 waves, 16 waves/CU.
  gemm_bt<false, true, 128><<<dim3(24, 32), 512, 0, stream>>>(
      xb, wqb, qkv, outk, outv, vt, 4096, 3072, 1024);
  // 2a. split-k flash attention: 63 parts/bh (even/odd k-tiles), <=16 steps
  attn<<<dim3(63, 32), 256, 0, stream>>>(qkv, vt, ao, poA, poB);
  // 2b. merge split partials -> ao (qt 1..31)
  merge_attn<<<dim3(31, 32), 256, 0, stream>>>(poA, poB, ao);
  // 3. out(fp32) = ao @ wob^T: 64x128 tile -> 512 blocks
  gemm_bt<true, false, 64><<<dim3(8, 64), 512, 0, stream>>>(
      ao, wob, out, nullptr, nullptr, nullptr, 4096, 1024, 1024);
}

// Round 15
// 190.928 us; speedup vs baseline: 1.0613x; 1.0613x over previous
//
#include <hip/hip_runtime.h>
#include <cstdint>

typedef unsigned short u16;
typedef __bf16 bf16x8 __attribute__((ext_vector_type(8)));
typedef float f32x4 __attribute__((ext_vector_type(4)));
typedef short s4 __attribute__((ext_vector_type(4)));

#define T_SEQ 2048
#define NH 16

// RTNE float -> bf16 bits
__device__ __forceinline__ u16 f2bf(float f) {
  union { float f; uint32_t u; } x; x.f = f;
  uint32_t r = (x.u + 0x7fffu + ((x.u >> 16) & 1u)) >> 16;
  return (u16)r;
}

// pack two floats -> two bf16 (RTNE)
__device__ __forceinline__ uint32_t pk2bf(float a, float b) {
  union { float f; uint32_t u; } x, y; x.f = a; y.f = b;
  uint32_t lo = (x.u + 0x7fffu + ((x.u >> 16) & 1u)) >> 16;
  uint32_t hi = (y.u + 0x7fffu + ((y.u >> 16) & 1u)) >> 16;
  return lo | (hi << 16);
}

// 8 fp32 -> 8 bf16 (one uint4 store)
__device__ __forceinline__ void cvt8(u16* dst, const float* src) {
  float4 a = *(const float4*)src;
  float4 b = *(const float4*)(src + 4);
  uint4 o;
  o.x = pk2bf(a.x, a.y); o.y = pk2bf(a.z, a.w);
  o.z = pk2bf(b.x, b.y); o.w = pk2bf(b.z, b.w);
  *(uint4*)dst = o;
}

// fused fp32 -> bf16 conversion of x, w_qkv, w_o (dst regions contiguous in ws)
__global__ __launch_bounds__(256) void cvt_all(const float* __restrict__ x,
                                               const float* __restrict__ wq,
                                               const float* __restrict__ wo,
                                               u16* __restrict__ dst) {
  int i = blockIdx.x * 256 + threadIdx.x;
  const float* src; int off;
  if (i < 524288)      { src = x;  off = 0; }
  else if (i < 917504) { src = wq; off = 524288; }
  else                 { src = wo; off = 917504; }
  cvt8(&dst[(size_t)i * 8], &src[(size_t)(i - off) * 8]);
}

// f32x4 accumulator quad -> 4 bf16
__device__ __forceinline__ s4 cvt4(f32x4 v) {
  union { __bf16 b[4]; s4 s; } u;
  u.b[0] = (__bf16)v[0]; u.b[1] = (__bf16)v[1];
  u.b[2] = (__bf16)v[2]; u.b[3] = (__bf16)v[3];
  return u.s;
}

__device__ __forceinline__ f32x4 mfma16(s4 a, s4 b, f32x4 c) {
#if __has_builtin(__builtin_amdgcn_mfma_f32_16x16x16bf16_1k)
  return __builtin_amdgcn_mfma_f32_16x16x16bf16_1k(a, b, c, 0, 0, 0);
#else
  asm("v_mfma_f32_16x16x16_bf16 %0, %1, %2, %0" : "+v"(c) : "v"(a), "v"(b));
  return c;
#endif
}

// native 2^x
__device__ __forceinline__ float exp2fast(float x) {
#if __has_builtin(__builtin_amdgcn_exp2f)
  return __builtin_amdgcn_exp2f(x);
#else
  float r; asm("v_exp_f32 %0, %1" : "=v"(r) : "v"(x)); return r;
#endif
}

// async 16B global -> LDS (HW scatters lane i at ldsbase + i*16)
__device__ __forceinline__ void gl_lds(const u16* g, u16* ldsbase) {
  __builtin_amdgcn_global_load_lds(
      (const __attribute__((address_space(1))) void*)g,
      (__attribute__((address_space(3))) void*)ldsbase, 16, 0, 0);
}

// C[M,N] = A[M,K] * W[N,K]^T. A,W bf16; C fp32 (CF32) or bf16 ws.
// KV: k cols (1024..2047) -> qkv bf16 + outk fp32; v cols (>=2048) ->
//     outv fp32 + TRANSPOSED bf16 into vt (fused transpose_v).
// tile BMx128, BK=32, 512 threads = 8 waves, each (BM/2)x32.
// ROUND-15: the attn-proven 3-buffer counted-vmcnt pipeline replaces the
// 2-phase drain-0 dbuf: per step  vmcnt(keep: stage(t+1) stays in flight)
// -> barrier -> issue stage(t+2) -> compute(t).  Loads get ~2 full steps to
// land instead of one 8-MFMA phase -> per-step stall gone.  BK=32 shrinks
// buffers so 3 of them fit: BM=128: 48 KB -> 3 blocks/CU (24 waves/CU);
// BM=64: 36 KB -> 4 blocks/CU.  Rows are 64B (4 chunks): swizzle
// chunk ^= row&3 -> 8 bank-slots over 16 lanes = 2-way conflict (free).
// Per-wave stage loads: BM=128: 2 (uniform); BM=64: waves 0-3: 2 (A+B),
// waves 4-7: 1 (B) -- each wave waits ITS OWN count; barrier gives
// cross-wave visibility (same discipline as attn, HW-proven rounds 4-12).
template <bool CF32, bool KV, int BM>
__global__ __launch_bounds__(512) void gemm_bt(
    const u16* __restrict__ A, const u16* __restrict__ W,
    void* __restrict__ Cp, float* __restrict__ outk, float* __restrict__ outv,
    u16* __restrict__ vtp, int M, int N, int K) {
  constexpr int WM = BM / 2;            // wave m-extent
  constexpr int MI = WM / 16;           // m-frags per wave
  constexpr int NJ = 2;                 // n-frags per wave (32 cols)
  __shared__ __align__(16) u16 As[3][BM * 32];
  __shared__ __align__(16) u16 Bs[3][128 * 32];
  const int tid  = threadIdx.x;
  const int bid  = blockIdx.y * gridDim.x + blockIdx.x;
  const int per  = (gridDim.x * gridDim.y) >> 3;
  const int swz  = (bid & 7) * per + (bid >> 3);
  const int n0   = (swz % gridDim.x) * 128;
  const int m0   = (swz / gridDim.x) * BM;
  const int lane = tid & 63;
  const int wave = tid >> 6;            // 0..7
  const int wm   = (wave >> 2) * WM;
  const int wn   = (wave & 3) * 32;
  const int l15  = lane & 15;
  const int quad = lane >> 4;
  const int srow = lane >> 2;           // 0..15: row within 16-row issue
  const int sc   = lane & 3;            // 16B chunk within 64B row
  const bool ldA = (BM == 128) || (wave < 4);  // this wave stages an A group

  f32x4 acc[MI][NJ];
#pragma unroll
  for (int i = 0; i < MI; i++)
#pragma unroll
    for (int j = 0; j < NJ; j++) acc[i][j] = (f32x4){0.f, 0.f, 0.f, 0.f};

  // stage K-step k0 into buffer buf: B 1 issue/wave; A 1 issue (ldA waves)
  auto stage = [&](int buf, int k0) {
    {
      int r0 = wave * 16, row = r0 + srow;
      int gc = (sc ^ (row & 3)) << 3;   // pre-swizzled source column (u16)
      gl_lds(&W[(size_t)(n0 + row) * K + k0 + gc], &Bs[buf][r0 * 32]);
    }
    if (ldA) {
      int r0 = wave * 16, row = r0 + srow;
      int gc = (sc ^ (row & 3)) << 3;
      gl_lds(&A[(size_t)(m0 + row) * K + k0 + gc], &As[buf][r0 * 32]);
    }
  };

  stage(0, 0);
  stage(1, 32);

  const int NT = K >> 5;
  for (int t = 0; t < NT; t++) {
    const int cur = t % 3;
    // retire stage(t); keep stage(t+1) in flight (per-wave count)
    if (t + 1 < NT) {
      if (ldA) asm volatile("s_waitcnt vmcnt(2)" ::: "memory");
      else     asm volatile("s_waitcnt vmcnt(1)" ::: "memory");
    } else {
      asm volatile("s_waitcnt vmcnt(0)" ::: "memory");
    }
    __builtin_amdgcn_s_barrier();       // stage(t) landed in all waves
    __builtin_amdgcn_sched_barrier(0);

    if (t + 2 < NT) stage((t + 2) % 3, (t + 2) * 32);  // overwrites buf[(t-1)%3]

    // compute K-step t from buf[cur] (swizzled 2-way-free reads)
    bf16x8 af[MI], bfr[NJ];
#pragma unroll
    for (int i = 0; i < MI; i++) {
      int arow = wm + i * 16 + l15;
      af[i] = *(const bf16x8*)((const char*)&As[cur][0] + arow * 64 +
                               ((quad ^ (arow & 3)) << 4));
    }
#pragma unroll
    for (int j = 0; j < NJ; j++) {
      int brow = wn + j * 16 + l15;
      bfr[j] = *(const bf16x8*)((const char*)&Bs[cur][0] + brow * 64 +
                                ((quad ^ (brow & 3)) << 4));
    }
    __builtin_amdgcn_s_setprio(1);
#pragma unroll
    for (int i = 0; i < MI; i++)
#pragma unroll
      for (int j = 0; j < NJ; j++)
        acc[i][j] = __builtin_amdgcn_mfma_f32_16x16x32_bf16(af[i], bfr[j], acc[i][j], 0, 0, 0);
    __builtin_amdgcn_s_setprio(0);
  }

#pragma unroll
  for (int i = 0; i < MI; i++)
#pragma unroll
    for (int j = 0; j < NJ; j++) {
      const int row0 = m0 + wm + i * 16 + quad * 4;  // 4 consecutive rows
      const int col  = n0 + wn + j * 16 + l15;
      if constexpr (CF32) {
#pragma unroll
        for (int r = 0; r < 4; r++)
          ((float*)Cp)[(size_t)(row0 + r) * N + col] = acc[i][j][r];
      } else if (KV && col >= 2048) {
        // v: fp32 output + transposed bf16 into vt (4 consecutive t -> 8B)
        const int hd = col - 2048;
        const int b_ = row0 >> 11, t_ = row0 & 2047;
        uint2 pk;
        pk.x = pk2bf(acc[i][j][0], acc[i][j][1]);
        pk.y = pk2bf(acc[i][j][2], acc[i][j][3]);
        *(uint2*)&vtp[((size_t)(b_ * NH + (hd >> 6)) * 64 + (hd & 63)) * 2048 + t_] = pk;
#pragma unroll
        for (int r = 0; r < 4; r++)
          outv[(size_t)(row0 + r) * 1024 + hd] = acc[i][j][r];
      } else {
#pragma unroll
        for (int r = 0; r < 4; r++) {
          float v = acc[i][j][r];
          ((u16*)Cp)[(size_t)(row0 + r) * N + col] = f2bf(v);
          if constexpr (KV) {
            if (col >= 1024) outk[(size_t)(row0 + r) * 1024 + (col - 1024)] = v;
          }
        }
      }
    }
}

// Flash-style causal attention, swapped QK^T (S^T = mfma(K,Q)).
// ONE 64-row q-tile per block (grid 32x32 = 1024 blocks -> 4 blocks/CU).
// 2-buffer K/V LDS pipeline (32 KB/block), one barrier/step, stage(s+1)
// issued right after the barrier.  Constant-sum balanced, per-head bijective
// q-tile assignment: co-resident quads {by, by+8, by+16, by+24} sum to 66.
// (Round-9/12 winner, 56.4 us, unchanged; split-k reverted after round-14
// showed it loses ~10 us: residency, not critical path, is the bound.)
__global__ __launch_bounds__(256) void attn(const u16* __restrict__ qkv,
                                            const u16* __restrict__ vt,
                                            u16* __restrict__ o) {
  __shared__ __align__(16) u16 Ks[2][64 * 64];
  __shared__ __align__(16) u16 Vts[2][64 * 64];

  const int tid  = threadIdx.x;
  const int bx   = blockIdx.x;          // 0..31
  const int by   = blockIdx.y;          // bh = b*16+h, 0..31
  const int b    = by >> 4, h = by & 15;
  const int lane = tid & 63, wave = tid >> 6;
  const int l15  = lane & 15, quad = lane >> 4;
  const int srow = lane >> 3, sc = lane & 7;
  const size_t qbase = (size_t)b * T_SEQ * 3072;
  const size_t vbase = (size_t)(b * NH + h) * 64 * 2048;
  const float C = 0.1803368801f;        // 0.125 * log2(e)

  // constant-sum balanced, per-head bijective q-tile assignment
  const int u  = (bx + (by & 7) * 5) & 31;
  const int c  = by >> 3;               // 0..3: co-resident quad index
  const int v_ = (u + ((c >> 1) << 4)) & 31;
  const int qt = (c & 1) ? (31 - v_) : v_;
  const int steps = qt + 1;

  const int wq0  = qt * 64 + wave * 16;
  const int qrow = wq0 + l15;

  // Q fragments (B-operand: n=l15 -> q row), loaded once from global
  const u16* qp = &qkv[qbase + (size_t)qrow * 3072 + h * 64];
  const bf16x8 qf0 = *(const bf16x8*)&qp[quad * 8];
  const bf16x8 qf1 = *(const bf16x8*)&qp[32 + quad * 8];

  f32x4 acc_o[4];
#pragma unroll
  for (int n = 0; n < 4; n++) acc_o[n] = (f32x4){0.f, 0.f, 0.f, 0.f};
  float m2run = -1e30f, lrun = 0.f;

  // async stage of k-tile kt into buffer buf: 4 gl_lds per wave
  auto stage = [&](int buf, int kt) {
    const int k0 = kt * 64;
#pragma unroll
    for (int i = 0; i < 2; i++) {
      int r0  = (wave * 2 + i) * 8;
      int row = r0 + srow;
      int gc  = (sc ^ (row & 7)) << 3;
      gl_lds(&qkv[qbase + (size_t)(k0 + row) * 3072 + 1024 + h * 64 + gc], &Ks[buf][r0 * 64]);
      gl_lds(&vt[vbase + (size_t)row * 2048 + k0 + gc], &Vts[buf][r0 * 64]);
    }
  };

  stage(0, 0);

  for (int s = 0; s < steps; s++) {
    const int cur = s & 1;
    asm volatile("s_waitcnt vmcnt(0)" ::: "memory");
    __builtin_amdgcn_s_barrier();
    __builtin_amdgcn_sched_barrier(0);

    if (s + 1 < steps) stage(cur ^ 1, s + 1);

    const int k0 = s * 64;

    // S^T[j]: row (quad*4+r) = k_local, col l15 = q  (swizzled Ks reads)
    f32x4 sacc[4];
#pragma unroll
    for (int j = 0; j < 4; j++) sacc[j] = (f32x4){0.f, 0.f, 0.f, 0.f};
    __builtin_amdgcn_s_setprio(1);
#pragma unroll
    for (int j = 0; j < 4; j++) {
      int krow = j * 16 + l15;
      const char* kb = (const char*)&Ks[cur][0] + krow * 128;
      bf16x8 kfa = *(const bf16x8*)(kb + ((quad ^ (krow & 7)) << 4));
      bf16x8 kfb = *(const bf16x8*)(kb + (((4 + quad) ^ (krow & 7)) << 4));
      sacc[j] = __builtin_amdgcn_mfma_f32_16x16x32_bf16(kfa, qf0, sacc[j], 0, 0, 0);
      sacc[j] = __builtin_amdgcn_mfma_f32_16x16x32_bf16(kfb, qf1, sacc[j], 0, 0, 0);
    }
    __builtin_amdgcn_s_setprio(0);

    if (s == qt) {  // diagonal tile: causal mask on raw scores
#pragma unroll
      for (int j = 0; j < 4; j++)
#pragma unroll
        for (int r = 0; r < 4; r++) {
          int k = k0 + j * 16 + quad * 4 + r;
          if (k > qrow) sacc[j][r] = -1e30f;
        }
    }

    // row max, tree-shaped
    float mj[4];
#pragma unroll
    for (int j = 0; j < 4; j++)
      mj[j] = fmaxf(fmaxf(sacc[j][0], sacc[j][1]), fmaxf(sacc[j][2], sacc[j][3]));
    float mx = fmaxf(fmaxf(mj[0], mj[1]), fmaxf(mj[2], mj[3]));
    mx = fmaxf(mx, __shfl_xor(mx, 16));
    mx = fmaxf(mx, __shfl_xor(mx, 32));
    const float m2x = mx * C;

    // defer-max: only rescale when the max grew by > 8 (log2 domain)
    if (!__all(m2x <= m2run + 8.0f)) {
      const float m2new = fmaxf(m2run, m2x);
      const float alpha = exp2fast(m2run - m2new);
      lrun *= alpha;
      m2run = m2new;
#pragma unroll
      for (int r = 0; r < 4; r++) {
        float ar = __shfl(alpha, quad * 4 + r);
#pragma unroll
        for (int n = 0; n < 4; n++) acc_o[n][r] *= ar;
      }
    }

    // p = exp2(s*C - m2run); tree sum
    const float nm = m2run;
    float ts[4];
#pragma unroll
    for (int j = 0; j < 4; j++) {
#pragma unroll
      for (int r = 0; r < 4; r++) sacc[j][r] = exp2fast(fmaf(sacc[j][r], C, -nm));
      ts[j] = (sacc[j][0] + sacc[j][1]) + (sacc[j][2] + sacc[j][3]);
    }
    float sum = (ts[0] + ts[1]) + (ts[2] + ts[3]);
    sum += __shfl_xor(sum, 16);
    sum += __shfl_xor(sum, 32);
    lrun += sum;

    // P -> bf16 A-frags (m=l15 -> q, k = quad*4+e), in-register
    s4 pa[4];
#pragma unroll
    for (int j = 0; j < 4; j++) pa[j] = cvt4(sacc[j]);

    // PV: B-frag = V^T[d = n*16+l15][k0 + j*16+quad*4 ..+3], swizzled b64
    __builtin_amdgcn_s_setprio(1);
#pragma unroll
    for (int j = 0; j < 4; j++)
#pragma unroll
      for (int n = 0; n < 4; n++) {
        int vrow = n * 16 + l15;
        int ch = (j * 2 + (quad >> 1)) ^ (vrow & 7);
        const s4 vf = *(const s4*)((const char*)&Vts[cur][0] + vrow * 128 +
                                   (ch << 4) + ((quad & 1) << 3));
        acc_o[n] = mfma16(pa[j], vf, acc_o[n]);
      }
    __builtin_amdgcn_s_setprio(0);
  }

  const float linv = 1.0f / lrun;
#pragma unroll
  for (int r = 0; r < 4; r++) {
    const float lr = __shfl(linv, quad * 4 + r);
    const int row = wq0 + quad * 4 + r;
#pragma unroll
    for (int n = 0; n < 4; n++)
      o[(size_t)(b * T_SEQ + row) * 1024 + h * 64 + n * 16 + l15] =
          f2bf(acc_o[n][r] * lr);
  }
}

extern "C" void kernel_launch(void* const* d_in, const int* in_sizes, int n_in,
                              void* d_out, int out_size, void* d_ws, size_t ws_size,
                              hipStream_t stream) {
  const float* x     = (const float*)d_in[0];   // (2,2048,1024) fp32
  const float* w_qkv = (const float*)d_in[1];   // (3072,1024)   fp32
  const float* w_o   = (const float*)d_in[2];   // (1024,1024)   fp32
  float* out  = (float*)d_out;                  // fp32 (4096,1024)
  float* outk = out + (size_t)4194304;
  float* outv = out + (size_t)8388608;

  u16* qkv = (u16*)d_ws;                        // 4096*3072
  u16* vt  = qkv + (size_t)4096 * 3072;         // 32*64*2048
  u16* ao  = vt  + (size_t)4194304;             // 4096*1024
  u16* xb  = ao  + (size_t)4194304;             // 4096*1024
  u16* wqb = xb  + (size_t)4194304;             // 3072*1024
  u16* wob = wqb + (size_t)3145728;             // 1024*1024

  // 0. fused fp32 -> bf16 conversion (xb, wqb, wob contiguous)
  cvt_all<<<4096, 256, 0, stream>>>(x, w_qkv, w_o, xb);

  // 1. qkv(bf16 ws) = xb @ wqb^T; k -> qkv+outk; v -> outv + vt (fused
  //    transpose).  128x128 tile, BK=32, 3-buf counted-vmcnt, 3 blocks/CU.
  gemm_bt<false, true, 128><<<dim3(24, 32), 512, 0, stream>>>(
      xb, wqb, qkv, outk, outv, vt, 4096, 3072, 1024);
  // 2. flash attention -> ao (bf16 ws): 1 tile/block, 1024 blocks, 2-buf pipe
  attn<<<dim3(32, 32), 256, 0, stream>>>(qkv, vt, ao);
  // 3. out(fp32) = ao @ wob^T: 64x128 tile, BK=32, 3-buf -> 4 blocks/CU
  gemm_bt<true, false, 64><<<dim3(8, 64), 512, 0, stream>>>(
      ao, wob, out, nullptr, nullptr, nullptr, 4096, 1024, 1024);
}